// Round 8
// baseline (116.550 us; speedup 1.0000x reference)
//
#include <hip/hip_runtime.h>
#include <hip/hip_fp16.h>

// BEV pooling: out[bin, c] = sum over points i with ranks_bev[i]==bin of
//                            depth_flat[ranks_depth[i]] * feat_flat[ranks_feat[i], c]
// ranks_bev is SORTED. The pool loop is VMEM-TRANSACTION-rate bound:
// coalescing is per-instruction into 64B granules, and 16 slots read 16
// random rows -> 16 transactions per feat instruction no matter the dtype
// (fp32: 5x16 feat + 16 depth + 2 idx = 98/iter; measured ~2.5 cy/trans).
// This round cuts 98 -> 50:
//   - feat packed to fp16 rows PADDED TO 192B (64B-aligned): whole row = 3
//     aligned granules -> 3 feat instrs x 16 = 48 trans (was 5x16).
//   - depth pre-gathered per point (wd[i] = depth[ranks_depth[i]]) by a
//     full-occupancy kernel (~3us, L2-rate); pool reads wd coalesced
//     (1 trans/iter) and drops rd entirely (was 16+1 trans/iter).
// Phases: 0a) gather_wd  0b) pack_feat_f16(192B rows)  1) seg lower_bound
//   2) ONE WAVE PER BIN, 16 slots x 4 lanes, R3-proven loop (per-lane early
//      exit + one-ahead index prefetch; source pipelining abandoned —
//      R1/R5/R6 proved hipcc re-sinks the loads regardless).
//      Epilogue: LDS transpose-reduce (R3 win), write offsets remapped to
//      the packed-row chunk ownership {2ll,2ll+1,8+2ll,9+2ll,16+ll}.
// Workspace tiers: A seg+featp+wd | B seg+featp | C seg only (exact R3 fp32).

#define CHN 80
#define SSTRIDE 84    // floats per slot row in LDS: 80 + 4 pad (16B-aligned)
#define ROWB 192      // padded fp16 feat row bytes (96 halves, 80 used)

struct __align__(8)  h4 { __half2 a, b; };          // 4 halves
struct __align__(16) h8 { __half2 a, b, c, d; };    // 8 halves

// wd[i] = depth[rd[i]] — full-occupancy random gather at L2 throughput.
__global__ __launch_bounds__(256)
void gather_wd(const float* __restrict__ depth, const int* __restrict__ rd,
               float* __restrict__ wd, int P) {
    int q = blockIdx.x * blockDim.x + threadIdx.x;
    int i4 = q * 4;
    if (i4 + 3 < P) {
        const int4 r = *reinterpret_cast<const int4*>(rd + i4);
        float4 o;
        o.x = depth[r.x]; o.y = depth[r.y]; o.z = depth[r.z]; o.w = depth[r.w];
        *reinterpret_cast<float4*>(wd + i4) = o;
    } else {
        for (int i = i4; i < P; ++i) wd[i] = depth[rd[i]];
    }
}

// featp row j (192B): halves 0..79 = fp16(feat row j), 80..95 = zero pad.
__global__ __launch_bounds__(256)
void pack_feat_f16(const float* __restrict__ feat, __half* __restrict__ featp,
                   int n_chunks /* n_rows * 24 (192B/8B chunks per row) */) {
    int q = blockIdx.x * blockDim.x + threadIdx.x;
    if (q >= n_chunks) return;
    const int j = q / 24;          // feat row
    const int c = q - j * 24;      // 8B chunk within padded row
    h4 o;
    if (c < 20) {
        const float4 v = *reinterpret_cast<const float4*>(feat + (size_t)j * CHN + c * 4);
        o.a = __floats2half2_rn(v.x, v.y);
        o.b = __floats2half2_rn(v.z, v.w);
    } else {
        o.a = __floats2half2_rn(0.f, 0.f);
        o.b = o.a;
    }
    *reinterpret_cast<h4*>(reinterpret_cast<char*>(featp) + (size_t)j * ROWB + c * 8) = o;
}

__global__ __launch_bounds__(256)
void seg_starts_kernel(const int* __restrict__ rb, int* __restrict__ seg,
                       int P, int total_bev) {
    int q = blockIdx.x * blockDim.x + threadIdx.x;   // quad index
    int i4 = q * 4;
    if (i4 >= P) return;
    const int4 v = *reinterpret_cast<const int4*>(rb + i4);
    int prev = (i4 == 0) ? -1 : rb[i4 - 1];
    int cur;
    cur = v.x; for (int b = prev + 1; b <= cur; ++b) seg[b] = i4 + 0; prev = cur;
    cur = v.y; for (int b = prev + 1; b <= cur; ++b) seg[b] = i4 + 1; prev = cur;
    cur = v.z; for (int b = prev + 1; b <= cur; ++b) seg[b] = i4 + 2; prev = cur;
    cur = v.w; for (int b = prev + 1; b <= cur; ++b) seg[b] = i4 + 3; prev = cur;
    if (i4 + 4 >= P) {
        for (int b = prev + 1; b <= total_bev; ++b) seg[b] = P;
    }
}

// MODE: 0 = fp32 feat + in-loop depth gather (exact R3 path)
//       1 = packed fp16 feat + in-loop depth gather
//       2 = packed fp16 feat + pre-gathered wd
template <int MODE>
__global__ __launch_bounds__(256)
void bev_pool_kernel(const float* __restrict__ depth,
                     const float* __restrict__ feat,
                     const __half* __restrict__ featp,
                     const float* __restrict__ wd,
                     const int* __restrict__ rd,
                     const int* __restrict__ rf,
                     const int* __restrict__ seg,
                     float* __restrict__ out,
                     int total_bev) {
    __shared__ float lds_buf[4][16 * SSTRIDE];       // per-wave-private 16x84 floats

    const int wave = threadIdx.x >> 6;               // 4 waves per block
    const int lane = threadIdx.x & 63;
    const int bin = blockIdx.x * 4 + wave;
    if (bin >= total_bev) return;

    const int slot = lane >> 2;                      // 0..15 point slot
    const int ll   = lane & 3;                       // 0..3 channel sub-lane

    const int lo = seg[bin];
    const int hi = seg[bin + 1];

    float4 a0 = make_float4(0.f, 0.f, 0.f, 0.f);
    float4 a1 = a0, a2 = a0, a3 = a0, a4 = a0;

    // R3-proven loop: per-lane early exit, one-ahead index prefetch.
    int i = lo + slot;
    bool valid = i < hi;
    int di = 0, fi = 0;
    float dv = 0.f;
    if (valid) {
        fi = rf[i];
        if constexpr (MODE == 2) dv = wd[i]; else di = rd[i];
    }
    while (valid) {
        const int ni = i + 16;
        const bool nvalid = ni < hi;
        int ndi = 0, nfi = 0;
        float ndv = 0.f;
        if (nvalid) {
            nfi = rf[ni];
            if constexpr (MODE == 2) ndv = wd[ni]; else ndi = rd[ni];
        }

        const float d = (MODE == 2) ? dv : depth[di];
        if constexpr (MODE >= 1) {
            // Padded row: 3 aligned granules. Lane ll owns chunks
            // {2ll, 2ll+1, 8+2ll, 9+2ll, 16+ll} (chunk = 4 channels).
            const char* rowp = reinterpret_cast<const char*>(featp) + (size_t)fi * ROWB;
            const h8 u0 = *reinterpret_cast<const h8*>(rowp + (ll << 4));        // ch 8ll..+7
            const h8 u1 = *reinterpret_cast<const h8*>(rowp + 64 + (ll << 4));   // ch 32+8ll..+7
            const h4 u2 = *reinterpret_cast<const h4*>(rowp + 128 + (ll << 3));  // ch 64+4ll..+3
            float2 p, q;
            p = __half22float2(u0.a); q = __half22float2(u0.b);
            a0.x += d*p.x; a0.y += d*p.y; a0.z += d*q.x; a0.w += d*q.y;
            p = __half22float2(u0.c); q = __half22float2(u0.d);
            a1.x += d*p.x; a1.y += d*p.y; a1.z += d*q.x; a1.w += d*q.y;
            p = __half22float2(u1.a); q = __half22float2(u1.b);
            a2.x += d*p.x; a2.y += d*p.y; a2.z += d*q.x; a2.w += d*q.y;
            p = __half22float2(u1.c); q = __half22float2(u1.d);
            a3.x += d*p.x; a3.y += d*p.y; a3.z += d*q.x; a3.w += d*q.y;
            p = __half22float2(u2.a); q = __half22float2(u2.b);
            a4.x += d*p.x; a4.y += d*p.y; a4.z += d*q.x; a4.w += d*q.y;
        } else {
            const float4* frow = reinterpret_cast<const float4*>(feat + (size_t)fi * CHN) + ll;
            const float4 f0 = frow[0];     // chunk ll
            const float4 f1 = frow[4];     // chunk ll+4
            const float4 f2 = frow[8];
            const float4 f3 = frow[12];
            const float4 f4 = frow[16];
            a0.x += d * f0.x; a0.y += d * f0.y; a0.z += d * f0.z; a0.w += d * f0.w;
            a1.x += d * f1.x; a1.y += d * f1.y; a1.z += d * f1.z; a1.w += d * f1.w;
            a2.x += d * f2.x; a2.y += d * f2.y; a2.z += d * f2.z; a2.w += d * f2.w;
            a3.x += d * f3.x; a3.y += d * f3.y; a3.z += d * f3.z; a3.w += d * f3.w;
            a4.x += d * f4.x; a4.y += d * f4.y; a4.z += d * f4.z; a4.w += d * f4.w;
        }

        i = ni; di = ndi; fi = nfi; dv = ndv; valid = nvalid;
    }

    // ---- Epilogue: LDS transpose-reduce (R3-proven); write offsets match
    // the mode's chunk ownership. All offsets 16B-aligned (SSTRIDE*4B=336).
    {
        float* wb = &lds_buf[wave][slot * SSTRIDE];
        if constexpr (MODE >= 1) {
            *reinterpret_cast<float4*>(wb + 8 * ll)      = a0;   // chunk 2ll
            *reinterpret_cast<float4*>(wb + 8 * ll + 4)  = a1;   // chunk 2ll+1
            *reinterpret_cast<float4*>(wb + 32 + 8 * ll) = a2;   // chunk 8+2ll
            *reinterpret_cast<float4*>(wb + 36 + 8 * ll) = a3;   // chunk 9+2ll
            *reinterpret_cast<float4*>(wb + 64 + 4 * ll) = a4;   // chunk 16+ll
        } else {
            *reinterpret_cast<float4*>(wb + 4 * ll)      = a0;   // chunk ll
            *reinterpret_cast<float4*>(wb + 4 * ll + 16) = a1;   // chunk ll+4
            *reinterpret_cast<float4*>(wb + 4 * ll + 32) = a2;   // chunk ll+8
            *reinterpret_cast<float4*>(wb + 4 * ll + 48) = a3;   // chunk ll+12
            *reinterpret_cast<float4*>(wb + 4 * ll + 64) = a4;   // chunk ll+16
        }
    }
    // Read: group g = lane>>5 sums slots g*8..g*8+7 of chunk c = lane&31
    // (active only for c < 20). Same-wave RAW: LDS ops retire in program
    // order within a wave; region is wave-private so no __syncthreads.
    const int g = lane >> 5;
    const int c = lane & 31;
    float4 r = make_float4(0.f, 0.f, 0.f, 0.f);
    if (c < 20) {
        const float* rp = &lds_buf[wave][g * 8 * SSTRIDE + c * 4];
        #pragma unroll
        for (int t = 0; t < 8; ++t) {
            const float4 v = *reinterpret_cast<const float4*>(rp + t * SSTRIDE);
            r.x += v.x; r.y += v.y; r.z += v.z; r.w += v.w;
        }
    }
    // Merge the two slot-halves: lanes 0..19 get lanes 32..51's partial.
    // Must run at top level (both groups active in the shfl).
    r.x += __shfl_xor(r.x, 32, 64);
    r.y += __shfl_xor(r.y, 32, 64);
    r.z += __shfl_xor(r.z, 32, 64);
    r.w += __shfl_xor(r.w, 32, 64);

    if (lane < 20) {
        *reinterpret_cast<float4*>(out + (size_t)bin * CHN + lane * 4) = r;
    }
}

extern "C" void kernel_launch(void* const* d_in, const int* in_sizes, int n_in,
                              void* d_out, int out_size, void* d_ws, size_t ws_size,
                              hipStream_t stream) {
    const float* depth = (const float*)d_in[0];
    const float* feat  = (const float*)d_in[1];
    const int*   rd    = (const int*)d_in[2];
    const int*   rf    = (const int*)d_in[3];
    const int*   rb    = (const int*)d_in[4];
    // d_in[5], d_in[6] (interval_starts/lengths) unused per reference; d_in[7] scalar total_bev.
    float* out = (float*)d_out;

    const int P = in_sizes[2];
    const int feat_elems = in_sizes[1];          // n_rows * 80 floats
    const int n_rows = feat_elems / CHN;         // 4224
    const int total_bev = out_size / CHN;        // 40000

    // Workspace layout: [seg][align][featp 192B rows][align][wd P floats]
    int* seg = (int*)d_ws;
    const size_t seg_bytes   = ((size_t)(total_bev + 1) * 4 + 255) & ~(size_t)255;
    const size_t featp_bytes = (((size_t)n_rows * ROWB) + 255) & ~(size_t)255;
    const size_t need_B = seg_bytes + featp_bytes;
    const size_t need_A = need_B + (size_t)P * 4;
    __half* featp = (__half*)((char*)d_ws + seg_bytes);
    float*  wd    = (float*)((char*)d_ws + seg_bytes + featp_bytes);

    const bool rows_ok = (feat_elems % CHN) == 0;
    const int mode = (!rows_ok) ? 0 : (ws_size >= need_A) ? 2 : (ws_size >= need_B) ? 1 : 0;

    const int quads = (P + 3) / 4;
    if (mode == 2) {
        gather_wd<<<(quads + 255) / 256, 256, 0, stream>>>(depth, rd, wd, P);
    }
    if (mode >= 1) {
        const int n_chunks = n_rows * 24;
        pack_feat_f16<<<(n_chunks + 255) / 256, 256, 0, stream>>>(feat, featp, n_chunks);
    }
    seg_starts_kernel<<<(quads + 255) / 256, 256, 0, stream>>>(rb, seg, P, total_bev);

    const int grid = (total_bev + 3) / 4;
    if (mode == 2) {
        bev_pool_kernel<2><<<grid, 256, 0, stream>>>(depth, feat, featp, wd, rd, rf, seg, out, total_bev);
    } else if (mode == 1) {
        bev_pool_kernel<1><<<grid, 256, 0, stream>>>(depth, feat, featp, wd, rd, rf, seg, out, total_bev);
    } else {
        bev_pool_kernel<0><<<grid, 256, 0, stream>>>(depth, feat, featp, wd, rd, rf, seg, out, total_bev);
    }
}